// Round 6
// baseline (255.283 us; speedup 1.0000x reference)
//
#include <hip/hip_runtime.h>
#include <hip/hip_bf16.h>

#define EPSBN 1e-5f

typedef short short8 __attribute__((ext_vector_type(8)));
typedef float f32x16 __attribute__((ext_vector_type(16)));

static __device__ __forceinline__ unsigned short f2u(float f){
  __hip_bfloat16 h = __float2bfloat16(f);
  union { __hip_bfloat16 h; unsigned short u; } c; c.h = h; return c.u;
}

// ---- workspace layout (bytes) ----
#define WS_G     2048
#define WS_S     7168
#define WS_T     8192
#define WS_AGGB  16384      // 147456 bf16  [b][cc2][s9][o32][ci32]
#define WS_XUP   327680     // 33554432 bf16 [b][h16(4)][r256][c256][ci16]  (plane = 1<<20 halfwords)

// ---------------- K1: weighted GAP (row-weight table computed inline) ----------------
__global__ __launch_bounds__(256) void k_gap(const float* __restrict__ x, float* __restrict__ g){
  __shared__ float w[128];
  __shared__ float partial[4];
  int tid = threadIdx.x;
  if (tid < 128){
    int i = tid;
    float s = 0.f;
    int rstart = max(0, (int)floorf((float)(i-1)*(255.0f/127.0f)));
    #pragma unroll
    for (int k = 0; k < 8; ++k){
      int r = rstart + k;
      if (r <= 255){
        float pos = (float)r * (127.0f/255.0f);
        int i0 = (int)pos; float fr = pos - (float)i0; int i1 = min(i0+1,127);
        if (i0 == i) s += 1.0f - fr;
        if (i1 == i) s += fr;
      }
    }
    w[i] = s;
  }
  __syncthreads();
  const float4* xp = (const float4*)(x + ((size_t)blockIdx.x << 14));
  float s = 0.f;
  for (int gi = tid; gi < 4096; gi += 256){
    int i = gi >> 5, j4 = (gi & 31) * 4;
    float4 v = xp[gi];
    s += (v.x*w[j4] + v.y*w[j4+1] + v.z*w[j4+2] + v.w*w[j4+3]) * w[i];
  }
  for (int off = 32; off > 0; off >>= 1) s += __shfl_down(s, off, 64);
  if ((tid & 63) == 0) partial[tid >> 6] = s;
  __syncthreads();
  if (tid == 0) g[blockIdx.x] = (partial[0]+partial[1]+partial[2]+partial[3]) * (1.0f/65536.0f);
}

// ------- K2: attention MLP (redundant per block) + aggregated bf16 filters -------
// layout out: [b][cc2][s9][o32][ci32]
__global__ __launch_bounds__(256) void k_aggw(const float* __restrict__ g,
                      const float* __restrict__ fc_w,
                      const float* __restrict__ bga, const float* __restrict__ bba,
                      const float* __restrict__ bma, const float* __restrict__ bva,
                      const float* __restrict__ ch_w, const float* __restrict__ ch_b,
                      const float* __restrict__ fil_w, const float* __restrict__ fil_b,
                      const float* __restrict__ sp_w, const float* __restrict__ sp_b,
                      const float* __restrict__ k_w, const float* __restrict__ k_b,
                      const float* __restrict__ bn_g, const float* __restrict__ bn_b,
                      const float* __restrict__ bn_m, const float* __restrict__ bn_v,
                      const float* __restrict__ weight,
                      unsigned short* __restrict__ aggb,
                      float* __restrict__ sS, float* __restrict__ tT)
{
  __shared__ float h[8][16];
  int tid = threadIdx.x;
  if (tid < 128){
    int b = tid >> 4, a = tid & 15;
    float acc = 0.f;
    for (int c = 0; c < 64; ++c) acc += g[b*64+c] * fc_w[a*64+c];
    float v = (acc - bma[a]) * rsqrtf(bva[a] + EPSBN) * bga[a] + bba[a];
    h[b][a] = fmaxf(v, 0.f);
  }
  __syncthreads();

  int idx = blockIdx.x*256 + tid;      // < 147456
  int ci_l = idx & 31;
  int o    = (idx >> 5) & 31;
  int s    = (idx >> 10) % 9;
  int t2   = (idx >> 10) / 9;          // b*2+cc
  int cc   = t2 & 1, b = t2 >> 1;
  int ci   = cc*32 + ci_l;

  const float* hb = h[b];
  float zc = ch_b[ci], zs = sp_b[s];
  float z0 = k_b[0],  z1 = k_b[1];
  #pragma unroll
  for (int a = 0; a < 16; ++a){
    float hv = hb[a];
    zc += hv*ch_w[ci*16+a];
    zs += hv*sp_w[s*16+a];
    z0 += hv*k_w[a];
    z1 += hv*k_w[16+a];
  }
  float chv = 1.f/(1.f+expf(-zc));
  float spv = 1.f/(1.f+expf(-zs));
  float m = fmaxf(z0,z1);
  float e0 = expf(z0-m), e1 = expf(z1-m), inv = 1.f/(e0+e1);
  float ka0 = e0*inv, ka1 = e1*inv;
  float w0 = weight[(o*64+ci)*9+s];
  float w1 = weight[((32+o)*64+ci)*9+s];
  aggb[idx] = f2u(chv*spv*(ka0*w0 + ka1*w1));

  if (blockIdx.x == 0){
    int bb = tid >> 5, oo = tid & 31;
    float z = fil_b[oo];
    #pragma unroll
    for (int a = 0; a < 16; ++a) z += h[bb][a]*fil_w[oo*16+a];
    float f = 1.f/(1.f+expf(-z));
    float invs = rsqrtf(bn_v[oo] + EPSBN);
    sS[tid] = f * bn_g[oo] * invs;
    if (bb == 0) tT[oo] = bn_b[oo] - bn_m[oo]*bn_g[oo]*invs;
  }
}

// -------- K3: bilinear x2 upsample -> bf16 planes [b][h16][r][c][ci16] --------
// grid: 1024 = b(8) x h16(4) x strip(32 of 8 rows); writes 1KB contiguous per wave.
__global__ __launch_bounds__(256) void k_up(const float* __restrict__ x,
                                            unsigned int* __restrict__ xup32)
{
  __shared__ float xin[16*798];     // [ci16][ir6][j133pad]
  int tid = threadIdx.x;
  int bi  = blockIdx.x;
  int strip = bi & 31, h16 = (bi >> 5) & 3, b = bi >> 7;
  int r0 = strip * 8;
  int i0b = (int)((float)r0 * (127.0f/255.0f));

  for (int e = tid; e < 12288; e += 256){
    int ir = e >> 11, rem = e & 2047, ci = rem >> 7, j = rem & 127;
    int row = min(i0b + ir, 127);
    xin[ci*798 + ir*133 + j] = x[(((size_t)(b*64 + h16*16 + ci)) << 14) + (row << 7) + j];
  }
  __syncthreads();

  int ci2 = tid & 7, cbase = tid >> 3;   // cbase 0..31
  int j0t[8], j1t[8]; float wwt[8];
  #pragma unroll
  for (int jj = 0; jj < 8; ++jj){
    int c = cbase + 32*jj;
    float pos = (float)c * (127.0f/255.0f);
    int j0 = (int)pos;
    j0t[jj] = j0; j1t[jj] = min(j0+1,127); wwt[jj] = pos - (float)j0;
  }
  const float* base0 = &xin[(ci2*2+0)*798];
  const float* base1 = &xin[(ci2*2+1)*798];
  size_t plane32 = ((size_t)(b*4 + h16)) << 19;   // plane base in dwords

  for (int rr = 0; rr < 8; ++rr){
    int r = r0 + rr;
    float posr = (float)r * (127.0f/255.0f);
    int i0 = (int)posr; float wh = posr - (float)i0;
    int ir0 = (i0 - i0b)*133, ir1 = (min(i0+1,127) - i0b)*133;
    #pragma unroll
    for (int jj = 0; jj < 8; ++jj){
      int c = cbase + 32*jj;
      int j0 = j0t[jj], j1 = j1t[jj]; float ww = wwt[jj];
      float v00 = base0[ir0+j0], v01 = base0[ir0+j1];
      float v10 = base0[ir1+j0], v11 = base0[ir1+j1];
      float a0 = v00 + (v01-v00)*ww;
      float a1 = v10 + (v11-v10)*ww;
      float r0v = a0 + (a1-a0)*wh;
      float u00 = base1[ir0+j0], u01 = base1[ir0+j1];
      float u10 = base1[ir1+j0], u11 = base1[ir1+j1];
      float b0 = u00 + (u01-u00)*ww;
      float b1 = u10 + (u11-u10)*ww;
      float r1v = b0 + (b1-b0)*wh;
      unsigned pack = (unsigned)f2u(r0v) | (((unsigned)f2u(r1v)) << 16);
      xup32[plane32 + (size_t)(r*256 + c)*8 + ci2] = pack;
    }
  }
}

// -------- K4: MFMA implicit-GEMM conv + BN + GELU --------
// block: 16x16 output px, all 32 Cout; 4 waves x 2 acc tiles; 2 cc chunks of 32 ci.
// A-fragments (weights) read directly from global (L2-resident) — no weight LDS.
#define XT_STRIDE 40   // 32 ci + 8 pad halfwords (80 B, 16B-aligned, bank-balanced)
__global__ __launch_bounds__(256, 5) void k_conv(const unsigned short* __restrict__ xup,
                                              const unsigned short* __restrict__ aggb,
                                              const float* __restrict__ sS,
                                              const float* __restrict__ tT,
                                              float* __restrict__ out)
{
  __shared__ unsigned short xt[18*18*XT_STRIDE];   // 25920 B
  __shared__ float sSs[32], tTs[32];

  int tid = threadIdx.x;
  int bi  = blockIdx.x;
  int b   = bi >> 8, t = bi & 255;
  int p0  = (t >> 4) * 16, q0 = (t & 15) * 16;
  int lane = tid & 63, wv = tid >> 6;
  if (tid < 32){ sSs[tid] = sS[b*32+tid]; tTs[tid] = tT[tid]; }

  // xt staging descriptors (cc-invariant): 1296 granules of 16B
  // e -> (rr, qq, k2, kq): rr=e/72, qq=(e%72)>>2, k2=(e>>1)&1, kq=e&1
  int ldsoff[6], pmoff[6]; bool val[6];
  int cnt = (tid < 16) ? 6 : 5;
  for (int k = 0; k < cnt; ++k){
    int e = tid + (k << 8);
    int rr = e / 72; int rem = e - rr*72;
    int qq = rem >> 2; int k2 = (rem >> 1) & 1; int kq = rem & 1;
    int gr = p0 - 1 + rr, gq = q0 - 1 + qq;
    val[k]    = ((unsigned)gr < 256u) && ((unsigned)gq < 256u);
    ldsoff[k] = (rr*18+qq)*XT_STRIDE + k2*16 + kq*8;
    pmoff[k]  = (k2 << 20) + (gr*256+gq)*16 + kq*8;
  }

  f32x16 acc[2];
  #pragma unroll
  for (int i = 0; i < 16; ++i){ acc[0][i] = 0.f; acc[1][i] = 0.f; }

  int n  = lane & 31;
  int kq = lane >> 5;

  for (int cc = 0; cc < 2; ++cc){
    if (cc) __syncthreads();
    const unsigned short* xb = xup + (((size_t)(b*4 + 2*cc)) << 20);
    for (int k = 0; k < cnt; ++k){
      short8 v = {0,0,0,0,0,0,0,0};
      if (val[k]) v = *(const short8*)&xb[pmoff[k]];
      *(short8*)&xt[ldsoff[k]] = v;
    }
    __syncthreads();

    // A base for this (b,cc): [s][o32][ci32]
    const unsigned short* ab = aggb + (((size_t)(b*2+cc))*9*32 + n)*32 + kq*8;

    #pragma unroll
    for (int s = 0; s < 9; ++s){
      const int ky = s / 3, kx = s % 3;
      const unsigned short* ap = ab + s*1024;
      short8 av0 = *(const short8*)&ap[0];    // k2=0 (ci 0..15)
      short8 av1 = *(const short8*)&ap[16];   // k2=1 (ci 16..31)
      #pragma unroll
      for (int tt = 0; tt < 2; ++tt){
        int lr = 2*(2*wv + tt) + (n >> 4);
        int rr = lr + ky;
        int qq = (n & 15) + kx;
        const unsigned short* xrow = &xt[(rr*18+qq)*XT_STRIDE + kq*8];
        short8 bv0 = *(const short8*)&xrow[0];
        short8 bv1 = *(const short8*)&xrow[16];
        acc[tt] = __builtin_amdgcn_mfma_f32_32x32x16_bf16(av0, bv0, acc[tt], 0, 0, 0);
        acc[tt] = __builtin_amdgcn_mfma_f32_32x32x16_bf16(av1, bv1, acc[tt], 0, 0, 0);
      }
    }
  }

  // epilogue: scale/bias + GELU(exact erf), fp32 stores
  #pragma unroll
  for (int tt = 0; tt < 2; ++tt){
    int lr = 2*(2*wv + tt) + (n >> 4);
    int p = p0 + lr, q = q0 + (n & 15);
    #pragma unroll
    for (int r = 0; r < 16; ++r){
      int o = (r & 3) + 8*(r >> 2) + 4*kq;
      float valv = acc[tt][r]*sSs[o] + tTs[o];
      float gl  = 0.5f*valv*(1.f + erff(valv*0.70710678118f));
      out[(((size_t)(b*32+o)) << 16) + (p << 8) + q] = gl;
    }
  }
}

extern "C" void kernel_launch(void* const* d_in, const int* in_sizes, int n_in,
                              void* d_out, int out_size, void* d_ws, size_t ws_size,
                              hipStream_t stream)
{
  const float* x     = (const float*)d_in[0];
  const float* fc_w  = (const float*)d_in[1];
  const float* bga   = (const float*)d_in[2];
  const float* bba   = (const float*)d_in[3];
  const float* bma   = (const float*)d_in[4];
  const float* bva   = (const float*)d_in[5];
  const float* ch_w  = (const float*)d_in[6];
  const float* ch_b  = (const float*)d_in[7];
  const float* fil_w = (const float*)d_in[8];
  const float* fil_b = (const float*)d_in[9];
  const float* sp_w  = (const float*)d_in[10];
  const float* sp_b  = (const float*)d_in[11];
  const float* k_w   = (const float*)d_in[12];
  const float* k_b   = (const float*)d_in[13];
  const float* weight= (const float*)d_in[14];
  const float* bn_g  = (const float*)d_in[15];
  const float* bn_b  = (const float*)d_in[16];
  const float* bn_m  = (const float*)d_in[17];
  const float* bn_v  = (const float*)d_in[18];

  char* ws = (char*)d_ws;
  float* g   = (float*)(ws + WS_G);
  float* sS  = (float*)(ws + WS_S);
  float* tT  = (float*)(ws + WS_T);
  unsigned short* aggb = (unsigned short*)(ws + WS_AGGB);
  unsigned short* xup  = (unsigned short*)(ws + WS_XUP);
  float* out = (float*)d_out;

  hipLaunchKernelGGL(k_gap,  dim3(512),  dim3(256), 0, stream, x, g);
  hipLaunchKernelGGL(k_aggw, dim3(576),  dim3(256), 0, stream, g, fc_w, bga, bba, bma, bva,
                     ch_w, ch_b, fil_w, fil_b, sp_w, sp_b, k_w, k_b,
                     bn_g, bn_b, bn_m, bn_v, weight, aggb, sS, tT);
  hipLaunchKernelGGL(k_up,   dim3(1024), dim3(256), 0, stream, x, (unsigned int*)xup);
  hipLaunchKernelGGL(k_conv, dim3(2048), dim3(256), 0, stream, xup, aggb, sS, tT, out);
}

// Round 7
// 201.268 us; speedup vs baseline: 1.2684x; 1.2684x over previous
//
#include <hip/hip_runtime.h>
#include <hip/hip_bf16.h>

#define EPSBN 1e-5f

typedef short short8 __attribute__((ext_vector_type(8)));
typedef float f32x16 __attribute__((ext_vector_type(16)));

static __device__ __forceinline__ unsigned short f2u(float f){
  __hip_bfloat16 h = __float2bfloat16(f);
  union { __hip_bfloat16 h; unsigned short u; } c; c.h = h; return c.u;
}

// ---- workspace layout (bytes) ----
#define WS_G     2048
#define WS_S     7168
#define WS_T     8192
#define WS_AGGB  16384      // 147456 bf16  [b][cc2][s9][o32][ci32]
#define WS_XUP   327680     // 33554432 bf16 [b][h16(4)][r256][c256][ci16]  (plane = 1<<20 halfwords)

// ---------------- K1: weighted GAP (row-weight table computed inline) ----------------
__global__ __launch_bounds__(256) void k_gap(const float* __restrict__ x, float* __restrict__ g){
  __shared__ float w[128];
  __shared__ float partial[4];
  int tid = threadIdx.x;
  if (tid < 128){
    int i = tid;
    float s = 0.f;
    int rstart = max(0, (int)floorf((float)(i-1)*(255.0f/127.0f)));
    #pragma unroll
    for (int k = 0; k < 8; ++k){
      int r = rstart + k;
      if (r <= 255){
        float pos = (float)r * (127.0f/255.0f);
        int i0 = (int)pos; float fr = pos - (float)i0; int i1 = min(i0+1,127);
        if (i0 == i) s += 1.0f - fr;
        if (i1 == i) s += fr;
      }
    }
    w[i] = s;
  }
  __syncthreads();
  const float4* xp = (const float4*)(x + ((size_t)blockIdx.x << 14));
  float s = 0.f;
  for (int gi = tid; gi < 4096; gi += 256){
    int i = gi >> 5, j4 = (gi & 31) * 4;
    float4 v = xp[gi];
    s += (v.x*w[j4] + v.y*w[j4+1] + v.z*w[j4+2] + v.w*w[j4+3]) * w[i];
  }
  for (int off = 32; off > 0; off >>= 1) s += __shfl_down(s, off, 64);
  if ((tid & 63) == 0) partial[tid >> 6] = s;
  __syncthreads();
  if (tid == 0) g[blockIdx.x] = (partial[0]+partial[1]+partial[2]+partial[3]) * (1.0f/65536.0f);
}

// ------- K2: attention MLP (redundant per block) + aggregated bf16 filters -------
// layout out: [b][cc2][s9][o32][ci32]
__global__ __launch_bounds__(256) void k_aggw(const float* __restrict__ g,
                      const float* __restrict__ fc_w,
                      const float* __restrict__ bga, const float* __restrict__ bba,
                      const float* __restrict__ bma, const float* __restrict__ bva,
                      const float* __restrict__ ch_w, const float* __restrict__ ch_b,
                      const float* __restrict__ fil_w, const float* __restrict__ fil_b,
                      const float* __restrict__ sp_w, const float* __restrict__ sp_b,
                      const float* __restrict__ k_w, const float* __restrict__ k_b,
                      const float* __restrict__ bn_g, const float* __restrict__ bn_b,
                      const float* __restrict__ bn_m, const float* __restrict__ bn_v,
                      const float* __restrict__ weight,
                      unsigned short* __restrict__ aggb,
                      float* __restrict__ sS, float* __restrict__ tT)
{
  __shared__ float h[8][16];
  int tid = threadIdx.x;
  if (tid < 128){
    int b = tid >> 4, a = tid & 15;
    float acc = 0.f;
    for (int c = 0; c < 64; ++c) acc += g[b*64+c] * fc_w[a*64+c];
    float v = (acc - bma[a]) * rsqrtf(bva[a] + EPSBN) * bga[a] + bba[a];
    h[b][a] = fmaxf(v, 0.f);
  }
  __syncthreads();

  int idx = blockIdx.x*256 + tid;      // < 147456
  int ci_l = idx & 31;
  int o    = (idx >> 5) & 31;
  int s    = (idx >> 10) % 9;
  int t2   = (idx >> 10) / 9;          // b*2+cc
  int cc   = t2 & 1, b = t2 >> 1;
  int ci   = cc*32 + ci_l;

  const float* hb = h[b];
  float zc = ch_b[ci], zs = sp_b[s];
  float z0 = k_b[0],  z1 = k_b[1];
  #pragma unroll
  for (int a = 0; a < 16; ++a){
    float hv = hb[a];
    zc += hv*ch_w[ci*16+a];
    zs += hv*sp_w[s*16+a];
    z0 += hv*k_w[a];
    z1 += hv*k_w[16+a];
  }
  float chv = 1.f/(1.f+expf(-zc));
  float spv = 1.f/(1.f+expf(-zs));
  float m = fmaxf(z0,z1);
  float e0 = expf(z0-m), e1 = expf(z1-m), inv = 1.f/(e0+e1);
  float ka0 = e0*inv, ka1 = e1*inv;
  float w0 = weight[(o*64+ci)*9+s];
  float w1 = weight[((32+o)*64+ci)*9+s];
  aggb[idx] = f2u(chv*spv*(ka0*w0 + ka1*w1));

  if (blockIdx.x == 0){
    int bb = tid >> 5, oo = tid & 31;
    float z = fil_b[oo];
    #pragma unroll
    for (int a = 0; a < 16; ++a) z += h[bb][a]*fil_w[oo*16+a];
    float f = 1.f/(1.f+expf(-z));
    float invs = rsqrtf(bn_v[oo] + EPSBN);
    sS[tid] = f * bn_g[oo] * invs;
    if (bb == 0) tT[oo] = bn_b[oo] - bn_m[oo]*bn_g[oo]*invs;
  }
}

// -------- K3: bilinear x2 upsample -> bf16 planes [b][h16][r][c][ci16] --------
// grid: 1024 = b(8) x h16(4) x strip(32 of 8 rows); writes 1KB contiguous per wave.
__global__ __launch_bounds__(256) void k_up(const float* __restrict__ x,
                                            unsigned int* __restrict__ xup32)
{
  __shared__ float xin[16*798];     // [ci16][ir6][j133pad]
  int tid = threadIdx.x;
  int bi  = blockIdx.x;
  int strip = bi & 31, h16 = (bi >> 5) & 3, b = bi >> 7;
  int r0 = strip * 8;
  int i0b = (int)((float)r0 * (127.0f/255.0f));

  for (int e = tid; e < 12288; e += 256){
    int ir = e >> 11, rem = e & 2047, ci = rem >> 7, j = rem & 127;
    int row = min(i0b + ir, 127);
    xin[ci*798 + ir*133 + j] = x[(((size_t)(b*64 + h16*16 + ci)) << 14) + (row << 7) + j];
  }
  __syncthreads();

  int ci2 = tid & 7, cbase = tid >> 3;   // cbase 0..31
  int j0t[8], j1t[8]; float wwt[8];
  #pragma unroll
  for (int jj = 0; jj < 8; ++jj){
    int c = cbase + 32*jj;
    float pos = (float)c * (127.0f/255.0f);
    int j0 = (int)pos;
    j0t[jj] = j0; j1t[jj] = min(j0+1,127); wwt[jj] = pos - (float)j0;
  }
  const float* base0 = &xin[(ci2*2+0)*798];
  const float* base1 = &xin[(ci2*2+1)*798];
  size_t plane32 = ((size_t)(b*4 + h16)) << 19;   // plane base in dwords

  for (int rr = 0; rr < 8; ++rr){
    int r = r0 + rr;
    float posr = (float)r * (127.0f/255.0f);
    int i0 = (int)posr; float wh = posr - (float)i0;
    int ir0 = (i0 - i0b)*133, ir1 = (min(i0+1,127) - i0b)*133;
    #pragma unroll
    for (int jj = 0; jj < 8; ++jj){
      int c = cbase + 32*jj;
      int j0 = j0t[jj], j1 = j1t[jj]; float ww = wwt[jj];
      float v00 = base0[ir0+j0], v01 = base0[ir0+j1];
      float v10 = base0[ir1+j0], v11 = base0[ir1+j1];
      float a0 = v00 + (v01-v00)*ww;
      float a1 = v10 + (v11-v10)*ww;
      float r0v = a0 + (a1-a0)*wh;
      float u00 = base1[ir0+j0], u01 = base1[ir0+j1];
      float u10 = base1[ir1+j0], u11 = base1[ir1+j1];
      float b0 = u00 + (u01-u00)*ww;
      float b1 = u10 + (u11-u10)*ww;
      float r1v = b0 + (b1-b0)*wh;
      unsigned pack = (unsigned)f2u(r0v) | (((unsigned)f2u(r1v)) << 16);
      xup32[plane32 + (size_t)(r*256 + c)*8 + ci2] = pack;
    }
  }
}

// -------- K4: MFMA implicit-GEMM conv + BN + GELU --------
// block: 16x16 output px, all 32 Cout; 4 waves x 2 acc tiles; 2 cc chunks of 32 ci.
// A-fragments (weights) read directly from global (L2-resident) — no weight LDS.
// NOTE: no min-waves clause — capping VGPRs caused scratch spills (R6: WRITE 3x).
#define XT_STRIDE 40   // 32 ci + 8 pad halfwords (80 B, 16B-aligned, bank-balanced)
__global__ __launch_bounds__(256) void k_conv(const unsigned short* __restrict__ xup,
                                              const unsigned short* __restrict__ aggb,
                                              const float* __restrict__ sS,
                                              const float* __restrict__ tT,
                                              float* __restrict__ out)
{
  __shared__ unsigned short xt[18*18*XT_STRIDE];   // 25920 B
  __shared__ float sSs[32], tTs[32];

  int tid = threadIdx.x;
  int bi  = blockIdx.x;
  int b   = bi >> 8, t = bi & 255;
  int p0  = (t >> 4) * 16, q0 = (t & 15) * 16;
  int lane = tid & 63, wv = tid >> 6;
  if (tid < 32){ sSs[tid] = sS[b*32+tid]; tTs[tid] = tT[tid]; }

  // xt staging descriptors (cc-invariant): 1296 granules of 16B
  int ldsoff[6], pmoff[6]; bool val[6];
  int cnt = (tid < 16) ? 6 : 5;
  for (int k = 0; k < cnt; ++k){
    int e = tid + (k << 8);
    int rr = e / 72; int rem = e - rr*72;
    int qq = rem >> 2; int k2 = (rem >> 1) & 1; int kq = rem & 1;
    int gr = p0 - 1 + rr, gq = q0 - 1 + qq;
    val[k]    = ((unsigned)gr < 256u) && ((unsigned)gq < 256u);
    ldsoff[k] = (rr*18+qq)*XT_STRIDE + k2*16 + kq*8;
    pmoff[k]  = (k2 << 20) + (gr*256+gq)*16 + kq*8;
  }

  f32x16 acc[2];
  #pragma unroll
  for (int i = 0; i < 16; ++i){ acc[0][i] = 0.f; acc[1][i] = 0.f; }

  int n  = lane & 31;
  int kq = lane >> 5;

  for (int cc = 0; cc < 2; ++cc){
    if (cc) __syncthreads();
    const unsigned short* xb = xup + (((size_t)(b*4 + 2*cc)) << 20);
    for (int k = 0; k < cnt; ++k){
      short8 v = {0,0,0,0,0,0,0,0};
      if (val[k]) v = *(const short8*)&xb[pmoff[k]];
      *(short8*)&xt[ldsoff[k]] = v;
    }
    __syncthreads();

    // A base for this (b,cc): [s][o32][ci32]
    const unsigned short* ab = aggb + (((size_t)(b*2+cc))*9*32 + n)*32 + kq*8;

    #pragma unroll
    for (int s = 0; s < 9; ++s){
      const int ky = s / 3, kx = s % 3;
      const unsigned short* ap = ab + s*1024;
      short8 av0 = *(const short8*)&ap[0];    // k2=0 (ci 0..15)
      short8 av1 = *(const short8*)&ap[16];   // k2=1 (ci 16..31)
      #pragma unroll
      for (int tt = 0; tt < 2; ++tt){
        int lr = 2*(2*wv + tt) + (n >> 4);
        int rr = lr + ky;
        int qq = (n & 15) + kx;
        const unsigned short* xrow = &xt[(rr*18+qq)*XT_STRIDE + kq*8];
        short8 bv0 = *(const short8*)&xrow[0];
        short8 bv1 = *(const short8*)&xrow[16];
        acc[tt] = __builtin_amdgcn_mfma_f32_32x32x16_bf16(av0, bv0, acc[tt], 0, 0, 0);
        acc[tt] = __builtin_amdgcn_mfma_f32_32x32x16_bf16(av1, bv1, acc[tt], 0, 0, 0);
      }
    }
  }

  // epilogue: scale/bias + GELU(exact erf), fp32 stores
  #pragma unroll
  for (int tt = 0; tt < 2; ++tt){
    int lr = 2*(2*wv + tt) + (n >> 4);
    int p = p0 + lr, q = q0 + (n & 15);
    #pragma unroll
    for (int r = 0; r < 16; ++r){
      int o = (r & 3) + 8*(r >> 2) + 4*kq;
      float valv = acc[tt][r]*sSs[o] + tTs[o];
      float gl  = 0.5f*valv*(1.f + erff(valv*0.70710678118f));
      out[(((size_t)(b*32+o)) << 16) + (p << 8) + q] = gl;
    }
  }
}

extern "C" void kernel_launch(void* const* d_in, const int* in_sizes, int n_in,
                              void* d_out, int out_size, void* d_ws, size_t ws_size,
                              hipStream_t stream)
{
  const float* x     = (const float*)d_in[0];
  const float* fc_w  = (const float*)d_in[1];
  const float* bga   = (const float*)d_in[2];
  const float* bba   = (const float*)d_in[3];
  const float* bma   = (const float*)d_in[4];
  const float* bva   = (const float*)d_in[5];
  const float* ch_w  = (const float*)d_in[6];
  const float* ch_b  = (const float*)d_in[7];
  const float* fil_w = (const float*)d_in[8];
  const float* fil_b = (const float*)d_in[9];
  const float* sp_w  = (const float*)d_in[10];
  const float* sp_b  = (const float*)d_in[11];
  const float* k_w   = (const float*)d_in[12];
  const float* k_b   = (const float*)d_in[13];
  const float* weight= (const float*)d_in[14];
  const float* bn_g  = (const float*)d_in[15];
  const float* bn_b  = (const float*)d_in[16];
  const float* bn_m  = (const float*)d_in[17];
  const float* bn_v  = (const float*)d_in[18];

  char* ws = (char*)d_ws;
  float* g   = (float*)(ws + WS_G);
  float* sS  = (float*)(ws + WS_S);
  float* tT  = (float*)(ws + WS_T);
  unsigned short* aggb = (unsigned short*)(ws + WS_AGGB);
  unsigned short* xup  = (unsigned short*)(ws + WS_XUP);
  float* out = (float*)d_out;

  hipLaunchKernelGGL(k_gap,  dim3(512),  dim3(256), 0, stream, x, g);
  hipLaunchKernelGGL(k_aggw, dim3(576),  dim3(256), 0, stream, g, fc_w, bga, bba, bma, bva,
                     ch_w, ch_b, fil_w, fil_b, sp_w, sp_b, k_w, k_b,
                     bn_g, bn_b, bn_m, bn_v, weight, aggb, sS, tT);
  hipLaunchKernelGGL(k_up,   dim3(1024), dim3(256), 0, stream, x, (unsigned int*)xup);
  hipLaunchKernelGGL(k_conv, dim3(2048), dim3(256), 0, stream, xup, aggb, sS, tT, out);
}

// Round 8
// 190.993 us; speedup vs baseline: 1.3366x; 1.0538x over previous
//
#include <hip/hip_runtime.h>
#include <hip/hip_bf16.h>

#define EPSBN 1e-5f

typedef short short8 __attribute__((ext_vector_type(8)));
typedef float f32x16 __attribute__((ext_vector_type(16)));

static __device__ __forceinline__ unsigned short f2u(float f){
  __hip_bfloat16 h = __float2bfloat16(f);
  union { __hip_bfloat16 h; unsigned short u; } c; c.h = h; return c.u;
}

// ---- workspace layout (bytes) ----
#define WS_G     2048
#define WS_S     7168
#define WS_T     8192
#define WS_AGGB  16384      // 147456 bf16  [b][cc2][s9][o32][ci32]
#define WS_XUP   327680     // 33554432 bf16 [b][h16(4)][r256][c256][ci16]  (plane = 1<<20 halfwords)

// ------- K1: bilinear x2 upsample -> bf16 planes [b][h16][r][c][ci16], GAP fused -------
// grid: 1024 = b(8) x h16(4) x strip(32 of 8 rows)
__global__ __launch_bounds__(256) void k_up(const float* __restrict__ x,
                                            unsigned int* __restrict__ xup32,
                                            float* __restrict__ g)
{
  __shared__ float xin[16*798];     // [ci16][ir6][j133pad]
  __shared__ float w[128];
  int tid = threadIdx.x;
  int bi  = blockIdx.x;
  int strip = bi & 31, h16 = (bi >> 5) & 3, b = bi >> 7;
  int r0 = strip * 8;
  int i0b = (int)((float)r0 * (127.0f/255.0f));

  if (tid < 128){
    int i = tid;
    float s = 0.f;
    int rstart = max(0, (int)floorf((float)(i-1)*(255.0f/127.0f)));
    #pragma unroll
    for (int k = 0; k < 8; ++k){
      int r = rstart + k;
      if (r <= 255){
        float pos = (float)r * (127.0f/255.0f);
        int i0 = (int)pos; float fr = pos - (float)i0; int i1 = min(i0+1,127);
        if (i0 == i) s += 1.0f - fr;
        if (i1 == i) s += fr;
      }
    }
    w[i] = s;
  }
  for (int e = tid; e < 12288; e += 256){
    int ir = e >> 11, rem = e & 2047, ci = rem >> 7, j = rem & 127;
    int row = min(i0b + ir, 127);
    xin[ci*798 + ir*133 + j] = x[(((size_t)(b*64 + h16*16 + ci)) << 14) + (row << 7) + j];
  }
  __syncthreads();

  // ---- GAP partial: rows 4*strip..4*strip+3 (disjoint across strips), from LDS ----
  {
    int ci_l = tid >> 4, kk = tid & 15;
    float s = 0.f;
    const float* base = &xin[ci_l*798];
    #pragma unroll
    for (int row = 0; row < 4; ++row){
      int grow = 4*strip + row;
      int ir = grow - i0b;          // in [0,5] by construction
      const float* rp = base + ir*133 + kk*8;
      float ss = 0.f;
      #pragma unroll
      for (int j = 0; j < 8; ++j) ss += rp[j]*w[kk*8+j];
      s += w[grow]*ss;
    }
    s += __shfl_down(s, 8, 16);
    s += __shfl_down(s, 4, 16);
    s += __shfl_down(s, 2, 16);
    s += __shfl_down(s, 1, 16);
    if (kk == 0) atomicAdd(&g[b*64 + h16*16 + ci_l], s*(1.0f/65536.0f));
  }

  // ---- interp phase ----
  int ci2 = tid & 7, cbase = tid >> 3;   // cbase 0..31
  int j0t[8], j1t[8]; float wwt[8];
  #pragma unroll
  for (int jj = 0; jj < 8; ++jj){
    int c = cbase + 32*jj;
    float pos = (float)c * (127.0f/255.0f);
    int j0 = (int)pos;
    j0t[jj] = j0; j1t[jj] = min(j0+1,127); wwt[jj] = pos - (float)j0;
  }
  const float* base0 = &xin[(ci2*2+0)*798];
  const float* base1 = &xin[(ci2*2+1)*798];
  size_t plane32 = ((size_t)(b*4 + h16)) << 19;   // plane base in dwords

  for (int rr = 0; rr < 8; ++rr){
    int r = r0 + rr;
    float posr = (float)r * (127.0f/255.0f);
    int i0 = (int)posr; float wh = posr - (float)i0;
    int ir0 = (i0 - i0b)*133, ir1 = (min(i0+1,127) - i0b)*133;
    #pragma unroll
    for (int jj = 0; jj < 8; ++jj){
      int c = cbase + 32*jj;
      int j0 = j0t[jj], j1 = j1t[jj]; float ww = wwt[jj];
      float v00 = base0[ir0+j0], v01 = base0[ir0+j1];
      float v10 = base0[ir1+j0], v11 = base0[ir1+j1];
      float a0 = v00 + (v01-v00)*ww;
      float a1 = v10 + (v11-v10)*ww;
      float r0v = a0 + (a1-a0)*wh;
      float u00 = base1[ir0+j0], u01 = base1[ir0+j1];
      float u10 = base1[ir1+j0], u11 = base1[ir1+j1];
      float b0 = u00 + (u01-u00)*ww;
      float b1 = u10 + (u11-u10)*ww;
      float r1v = b0 + (b1-b0)*wh;
      unsigned pack = (unsigned)f2u(r0v) | (((unsigned)f2u(r1v)) << 16);
      xup32[plane32 + (size_t)(r*256 + c)*8 + ci2] = pack;
    }
  }
}

// ------- K2: attention MLP (redundant per block) + aggregated bf16 filters -------
// layout out: [b][cc2][s9][o32][ci32]
__global__ __launch_bounds__(256) void k_aggw(const float* __restrict__ g,
                      const float* __restrict__ fc_w,
                      const float* __restrict__ bga, const float* __restrict__ bba,
                      const float* __restrict__ bma, const float* __restrict__ bva,
                      const float* __restrict__ ch_w, const float* __restrict__ ch_b,
                      const float* __restrict__ fil_w, const float* __restrict__ fil_b,
                      const float* __restrict__ sp_w, const float* __restrict__ sp_b,
                      const float* __restrict__ k_w, const float* __restrict__ k_b,
                      const float* __restrict__ bn_g, const float* __restrict__ bn_b,
                      const float* __restrict__ bn_m, const float* __restrict__ bn_v,
                      const float* __restrict__ weight,
                      unsigned short* __restrict__ aggb,
                      float* __restrict__ sS, float* __restrict__ tT)
{
  __shared__ float h[8][16];
  int tid = threadIdx.x;
  if (tid < 128){
    int b = tid >> 4, a = tid & 15;
    float acc = 0.f;
    for (int c = 0; c < 64; ++c) acc += g[b*64+c] * fc_w[a*64+c];
    float v = (acc - bma[a]) * rsqrtf(bva[a] + EPSBN) * bga[a] + bba[a];
    h[b][a] = fmaxf(v, 0.f);
  }
  __syncthreads();

  int idx = blockIdx.x*256 + tid;      // < 147456
  int ci_l = idx & 31;
  int o    = (idx >> 5) & 31;
  int s    = (idx >> 10) % 9;
  int t2   = (idx >> 10) / 9;          // b*2+cc
  int cc   = t2 & 1, b = t2 >> 1;
  int ci   = cc*32 + ci_l;

  const float* hb = h[b];
  float zc = ch_b[ci], zs = sp_b[s];
  float z0 = k_b[0],  z1 = k_b[1];
  #pragma unroll
  for (int a = 0; a < 16; ++a){
    float hv = hb[a];
    zc += hv*ch_w[ci*16+a];
    zs += hv*sp_w[s*16+a];
    z0 += hv*k_w[a];
    z1 += hv*k_w[16+a];
  }
  float chv = 1.f/(1.f+expf(-zc));
  float spv = 1.f/(1.f+expf(-zs));
  float m = fmaxf(z0,z1);
  float e0 = expf(z0-m), e1 = expf(z1-m), inv = 1.f/(e0+e1);
  float ka0 = e0*inv, ka1 = e1*inv;
  float w0 = weight[(o*64+ci)*9+s];
  float w1 = weight[((32+o)*64+ci)*9+s];
  aggb[idx] = f2u(chv*spv*(ka0*w0 + ka1*w1));

  if (blockIdx.x == 0){
    int bb = tid >> 5, oo = tid & 31;
    float z = fil_b[oo];
    #pragma unroll
    for (int a = 0; a < 16; ++a) z += h[bb][a]*fil_w[oo*16+a];
    float f = 1.f/(1.f+expf(-z));
    float invs = rsqrtf(bn_v[oo] + EPSBN);
    sS[tid] = f * bn_g[oo] * invs;
    if (bb == 0) tT[oo] = bn_b[oo] - bn_m[oo]*bn_g[oo]*invs;
  }
}

// -------- K3: MFMA implicit-GEMM conv + BN + GELU --------
// block: 16x16 output px, all 32 Cout; 4 waves x 2 acc tiles; 2 cc chunks of 32 ci.
// cc=1 input tile prefetched into registers before cc=0 K-loop; A-frags s-pipelined.
#define XT_STRIDE 40   // 32 ci + 8 pad halfwords (80 B, 16B-aligned, bank-balanced)

static __device__ __forceinline__ void xdesc(int e, int p0, int q0,
                                             int& ldso, int& pmo, bool& v){
  int rr = e / 72; int rem = e - rr*72;
  int qq = rem >> 2; int k2 = (rem >> 1) & 1; int kqe = rem & 1;
  int gr = p0 - 1 + rr, gq = q0 - 1 + qq;
  v    = ((unsigned)gr < 256u) && ((unsigned)gq < 256u);
  ldso = (rr*18+qq)*XT_STRIDE + k2*16 + kqe*8;
  pmo  = (k2 << 20) + (gr*256+gq)*16 + kqe*8;
}

__global__ __launch_bounds__(256) void k_conv(const unsigned short* __restrict__ xup,
                                              const unsigned short* __restrict__ aggb,
                                              const float* __restrict__ sS,
                                              const float* __restrict__ tT,
                                              float* __restrict__ out)
{
  __shared__ unsigned short xt[18*18*XT_STRIDE];   // 25920 B
  __shared__ float sSs[32], tTs[32];

  int tid = threadIdx.x;
  int bi  = blockIdx.x;
  int b   = bi >> 8, t = bi & 255;
  int p0  = (t >> 4) * 16, q0 = (t & 15) * 16;
  int lane = tid & 63, wv = tid >> 6;
  if (tid < 32){ sSs[tid] = sS[b*32+tid]; tTs[tid] = tT[tid]; }

  f32x16 acc[2];
  #pragma unroll
  for (int i = 0; i < 16; ++i){ acc[0][i] = 0.f; acc[1][i] = 0.f; }

  int n  = lane & 31;
  int kq = lane >> 5;
  int lr0 = 2*(2*wv + 0) + (n >> 4);
  int lr1 = 2*(2*wv + 1) + (n >> 4);
  int qb  = n & 15;

  const unsigned short* xb0 = xup + (((size_t)(b*4 + 0)) << 20);
  const unsigned short* xb1 = xup + (((size_t)(b*4 + 2)) << 20);
  const short8 zero8 = {0,0,0,0,0,0,0,0};

  // stage cc=0 tile (6 independent granules per thread; wrap duplicates are benign)
  #pragma unroll
  for (int k = 0; k < 6; ++k){
    int e = tid + (k << 8); if (e >= 1296) e -= 1296;
    int ldso, pmo; bool v;
    xdesc(e, p0, q0, ldso, pmo, v);
    short8 vv = zero8;
    if (v) vv = *(const short8*)&xb0[pmo];
    *(short8*)&xt[ldso] = vv;
  }
  // prefetch cc=1 tile into registers (latency hides under cc=0 K-loop)
  short8 pre[6];
  #pragma unroll
  for (int k = 0; k < 6; ++k){
    int e = tid + (k << 8); if (e >= 1296) e -= 1296;
    int ldso, pmo; bool v;
    xdesc(e, p0, q0, ldso, pmo, v);
    pre[k] = zero8;
    if (v) pre[k] = *(const short8*)&xb1[pmo];
  }
  __syncthreads();

  // K-loop over a cc chunk; A-fragments software-pipelined (next-s loads in flight)
  auto kloop = [&](const unsigned short* ab){
    short8 a0 = *(const short8*)&ab[0];
    short8 a1 = *(const short8*)&ab[16];
    #pragma unroll
    for (int s = 0; s < 9; ++s){
      int sn = (s < 8) ? s+1 : 8;
      short8 na0 = *(const short8*)&ab[sn*1024];
      short8 na1 = *(const short8*)&ab[sn*1024+16];
      const int ky = s/3, kx = s%3;
      {
        const unsigned short* xrow = &xt[((lr0+ky)*18 + qb+kx)*XT_STRIDE + kq*8];
        short8 bv0 = *(const short8*)&xrow[0];
        short8 bv1 = *(const short8*)&xrow[16];
        acc[0] = __builtin_amdgcn_mfma_f32_32x32x16_bf16(a0, bv0, acc[0], 0, 0, 0);
        acc[0] = __builtin_amdgcn_mfma_f32_32x32x16_bf16(a1, bv1, acc[0], 0, 0, 0);
      }
      {
        const unsigned short* xrow = &xt[((lr1+ky)*18 + qb+kx)*XT_STRIDE + kq*8];
        short8 bv0 = *(const short8*)&xrow[0];
        short8 bv1 = *(const short8*)&xrow[16];
        acc[1] = __builtin_amdgcn_mfma_f32_32x32x16_bf16(a0, bv0, acc[1], 0, 0, 0);
        acc[1] = __builtin_amdgcn_mfma_f32_32x32x16_bf16(a1, bv1, acc[1], 0, 0, 0);
      }
      a0 = na0; a1 = na1;
    }
  };

  kloop(aggb + (size_t)(b*2+0)*9216 + n*32 + kq*8);
  __syncthreads();
  // commit prefetched cc=1 tile
  #pragma unroll
  for (int k = 0; k < 6; ++k){
    int e = tid + (k << 8); if (e >= 1296) e -= 1296;
    int ldso, pmo; bool v;
    xdesc(e, p0, q0, ldso, pmo, v);
    *(short8*)&xt[ldso] = pre[k];
  }
  __syncthreads();
  kloop(aggb + (size_t)(b*2+1)*9216 + n*32 + kq*8);

  // epilogue: scale/bias + GELU(exact erf), fp32 stores
  #pragma unroll
  for (int tt = 0; tt < 2; ++tt){
    int lr = (tt == 0) ? lr0 : lr1;
    int p = p0 + lr, q = q0 + qb;
    #pragma unroll
    for (int r = 0; r < 16; ++r){
      int o = (r & 3) + 8*(r >> 2) + 4*kq;
      float valv = acc[tt][r]*sSs[o] + tTs[o];
      float gl  = 0.5f*valv*(1.f + erff(valv*0.70710678118f));
      out[(((size_t)(b*32+o)) << 16) + (p << 8) + q] = gl;
    }
  }
}

extern "C" void kernel_launch(void* const* d_in, const int* in_sizes, int n_in,
                              void* d_out, int out_size, void* d_ws, size_t ws_size,
                              hipStream_t stream)
{
  const float* x     = (const float*)d_in[0];
  const float* fc_w  = (const float*)d_in[1];
  const float* bga   = (const float*)d_in[2];
  const float* bba   = (const float*)d_in[3];
  const float* bma   = (const float*)d_in[4];
  const float* bva   = (const float*)d_in[5];
  const float* ch_w  = (const float*)d_in[6];
  const float* ch_b  = (const float*)d_in[7];
  const float* fil_w = (const float*)d_in[8];
  const float* fil_b = (const float*)d_in[9];
  const float* sp_w  = (const float*)d_in[10];
  const float* sp_b  = (const float*)d_in[11];
  const float* k_w   = (const float*)d_in[12];
  const float* k_b   = (const float*)d_in[13];
  const float* weight= (const float*)d_in[14];
  const float* bn_g  = (const float*)d_in[15];
  const float* bn_b  = (const float*)d_in[16];
  const float* bn_m  = (const float*)d_in[17];
  const float* bn_v  = (const float*)d_in[18];

  char* ws = (char*)d_ws;
  float* g   = (float*)(ws + WS_G);
  float* sS  = (float*)(ws + WS_S);
  float* tT  = (float*)(ws + WS_T);
  unsigned short* aggb = (unsigned short*)(ws + WS_AGGB);
  unsigned short* xup  = (unsigned short*)(ws + WS_XUP);
  float* out = (float*)d_out;

  hipMemsetAsync(g, 0, 512*sizeof(float), stream);
  hipLaunchKernelGGL(k_up,   dim3(1024), dim3(256), 0, stream, x, (unsigned int*)xup, g);
  hipLaunchKernelGGL(k_aggw, dim3(576),  dim3(256), 0, stream, g, fc_w, bga, bba, bma, bva,
                     ch_w, ch_b, fil_w, fil_b, sp_w, sp_b, k_w, k_b,
                     bn_g, bn_b, bn_m, bn_v, weight, aggb, sS, tT);
  hipLaunchKernelGGL(k_conv, dim3(2048), dim3(256), 0, stream, xup, aggb, sS, tT, out);
}